// Round 13
// baseline (135.647 us; speedup 1.0000x reference)
//
#include <hip/hip_runtime.h>
#include <hip/hip_fp16.h>
#include <math.h>

#define HEADS 8
#define DIM 32
#define NEG_SLOPE 0.2f

typedef float f32x4 __attribute__((ext_vector_type(4)));

__device__ inline float2 u2f2(unsigned int u) {
    __half2 h = __builtin_bit_cast(__half2, u);
    return __half22float2(h);
}
__device__ inline unsigned short f2bf(float f) {       // RNE f32 -> bf16
    unsigned int u = __builtin_bit_cast(unsigned int, f);
    u += 0x7FFFu + ((u >> 16) & 1u);
    return (unsigned short)(u >> 16);
}
__device__ inline float bf2f(unsigned short b) {
    unsigned int u = ((unsigned int)b) << 16;
    return __builtin_bit_cast(float, u);
}

// Prep (merged): blocks [0, nb_logits): one wave per node — logits el/er in
// [node][8] layout and fp16 feat in per-head chunks feat_ph[h][node][32]
// (64B per (h,node), the XCD partition).
// Blocks [nb_logits, ...): CSR rowptr from sorted dst_idx (edge-parallel).
__global__ __launch_bounds__(256) void gat_prep_kernel(
    const float4* __restrict__ feat4,    // node row = 64 float4
    const float4* __restrict__ attn_l4,  // 64 float4 (8 heads x 8)
    const float4* __restrict__ attn_r4,
    float* __restrict__ el_n,            // [n_nodes][8]
    float* __restrict__ er_n,            // [n_nodes][8]
    uint2* __restrict__ feat_ph2,        // [8][n_nodes][8] uint2
    const int* __restrict__ dst,
    int* __restrict__ rowptr,
    int n_nodes, int n_edges, int nb_logits) {
    int b = blockIdx.x;
    if (b < nb_logits) {
        int wid = (b * 256 + threadIdx.x) >> 6;
        if (wid >= n_nodes) return;
        int lane = threadIdx.x & 63;
        int h = lane >> 3;
        int q = lane & 7;

        float4 al = attn_l4[lane];
        float4 ar = attn_r4[lane];
        float4 v  = feat4[(size_t)wid * 64 + lane];

        float sl = v.x * al.x + v.y * al.y + v.z * al.z + v.w * al.w;
        float sr = v.x * ar.x + v.y * ar.y + v.z * ar.z + v.w * ar.w;
#pragma unroll
        for (int off = 1; off < 8; off <<= 1) {
            sl += __shfl_xor(sl, off, 64);
            sr += __shfl_xor(sr, off, 64);
        }
        if (q == 0) {
            el_n[(unsigned)wid * 8 + h] = sl;
            er_n[(unsigned)wid * 8 + h] = sr;
        }
        unsigned hN = (unsigned)h * (unsigned)n_nodes;
        uint2 o;
        o.x = __builtin_bit_cast(unsigned int, __floats2half2_rn(v.x, v.y));
        o.y = __builtin_bit_cast(unsigned int, __floats2half2_rn(v.z, v.w));
        feat_ph2[((size_t)hN + (unsigned)wid) * 8 + q] = o;
    } else {
        int e = (b - nb_logits) * 256 + threadIdx.x;
        if (e >= n_edges) return;
        int d = dst[e];
        int prev = (e > 0) ? dst[e - 1] : -1;
        for (int v = prev + 1; v <= d; ++v) rowptr[v] = e;
        if (e == n_edges - 1) {
            for (int v = d + 1; v <= n_nodes; ++v) rowptr[v] = n_edges;
        }
    }
}

// wden: one wave per dst node. Lane (s = lane>>3 edge-slot, h = lane&7).
// Pass 1: w = exp(lrelu(el[u]+er[v])) stored bf16 head-major a_ph[h][E];
// den accumulated from the ROUNDED w (so sum(a)=1 tightly); shfl_xor butterfly
// over the 8 slots. Pass 2: rescale in place a = w * (1/den).
// Head-major layout -> XCD h later fetches only its own 1.6MB plane.
__global__ __launch_bounds__(256) void gat_wden_kernel(
    const float* __restrict__ el_n,      // [n_nodes][8]
    const float* __restrict__ er_n,      // [n_nodes][8]
    const int* __restrict__ src_idx,
    const int* __restrict__ rowptr,
    unsigned short* __restrict__ a_ph,   // [8][n_edges]
    int n_nodes, int n_edges) {
    int vraw = (blockIdx.x * blockDim.x + threadIdx.x) >> 6;
    if (vraw >= n_nodes) return;
    int v = __builtin_amdgcn_readfirstlane(vraw);
    int lane = threadIdx.x & 63;
    int s = lane >> 3;
    int h = lane & 7;

    int start = __builtin_amdgcn_readfirstlane(rowptr[v]);
    int end   = __builtin_amdgcn_readfirstlane(rowptr[v + 1]);
    if (start == end) return;

    float er_vh = er_n[(unsigned)v * 8 + h];
    size_t hE = (size_t)h * (unsigned)n_edges;

    float den = 0.f;
    for (int e0 = start; e0 < end; e0 += 8) {
        int e = e0 + s;
        int ee = e < end ? e : (end - 1);
        int u = src_idx[ee];
        float sc = el_n[(unsigned)u * 8 + h] + er_vh;
        sc = fmaxf(sc, NEG_SLOPE * sc);
        float w = __expf(sc);
        unsigned short wb = f2bf(w);
        if (e < end) {
            a_ph[hE + (unsigned)e] = wb;
            den += bf2f(wb);
        }
    }
    den += __shfl_xor(den, 8, 64);
    den += __shfl_xor(den, 16, 64);
    den += __shfl_xor(den, 32, 64);
    float inv = 1.f / den;
    for (int e0 = start; e0 < end; e0 += 8) {
        int e = e0 + s;
        if (e < end) {
            unsigned short wb = a_ph[hE + (unsigned)e];
            a_ph[hE + (unsigned)e] = f2bf(bf2f(wb) * inv);
        }
    }
}

// Aggregate: head h = blockIdx.x & 7 (XCD-resident 3.2MB feat chunk, proven
// R10/R12: FETCH 253->34MB). GROUP-PER-SEGMENT: wave = 8 whole segments for
// head h; lane (g = lane>>3 segment, q = lane&7 dims). Each lane accumulates
// its own 4 dims over its segment's edges -> NO cross-lane reduce, direct
// 128B/group store. Weights prenormalized (wden) -> no exp/den/divide.
// Loop to wave-max segment length; clamp + zero-weight predication.
__global__ __launch_bounds__(256) void gat_aggregate_kernel(
    const uint2* __restrict__ feat_ph2,        // [8][n_nodes][8] uint2
    const unsigned short* __restrict__ a_ph,   // [8][n_edges] prenormalized
    const int* __restrict__ src_idx,
    const int* __restrict__ rowptr,
    f32x4* __restrict__ out4,                  // [n_nodes*64]
    int n_nodes, int n_edges) {
    int b = blockIdx.x;
    int h = b & 7;                       // XCD-partitioned head
    int wave = (b >> 3) * 4 + (threadIdx.x >> 6);   // per-head wave index
    int lane = threadIdx.x & 63;
    int g = lane >> 3;                   // segment slot 0..7
    int q = lane & 7;                    // uint2 within 64B chunk

    int v = wave * 8 + g;                // this lane's dst node
    bool vok = v < n_nodes;
    int vv = vok ? v : (n_nodes - 1);

    int start = rowptr[vv];
    int len   = rowptr[vv + 1] - start;
    if (!vok) len = 0;
    if (len == 0) start = 0;             // keep gather addresses valid
    int lenm1 = (len > 0 ? len : 1) - 1; // >= 0

    // wave-wide max segment length (uniform loop bound)
    int ml = len;
    ml = max(ml, __shfl_xor(ml, 8, 64));
    ml = max(ml, __shfl_xor(ml, 16, 64));
    ml = max(ml, __shfl_xor(ml, 32, 64));
    int maxlen = __builtin_amdgcn_readfirstlane(ml);

    unsigned hN = (unsigned)h * (unsigned)n_nodes;
    size_t   hE = (size_t)h * (unsigned)n_edges;

    f32x4 acc0 = {0.f, 0.f, 0.f, 0.f};
    f32x4 acc1 = {0.f, 0.f, 0.f, 0.f};

    for (int i = 0; i < maxlen; i += 4) {
#pragma unroll
        for (int j = 0; j < 4; ++j) {
            int ii = i + j;
            int io = ii < lenm1 ? ii : lenm1;
            int e  = start + io;
            float a = bf2f(a_ph[hE + (unsigned)e]);
            a = (ii < len) ? a : 0.f;
            int u = src_idx[e];
            uint2 f = feat_ph2[((size_t)hN + (unsigned)u) * 8 + q];
            float2 lo = u2f2(f.x);
            float2 hi = u2f2(f.y);
            if (j & 1) {
                acc1.x += a * lo.x; acc1.y += a * lo.y;
                acc1.z += a * hi.x; acc1.w += a * hi.y;
            } else {
                acc0.x += a * lo.x; acc0.y += a * lo.y;
                acc0.z += a * hi.x; acc0.w += a * hi.y;
            }
        }
    }
    if (vok) {
        f32x4 r = acc0 + acc1;
        __builtin_nontemporal_store(
            r, &out4[((unsigned)v << 6) + ((unsigned)h << 3) + (unsigned)q]);
    }
}

extern "C" void kernel_launch(void* const* d_in, const int* in_sizes, int n_in,
                              void* d_out, int out_size, void* d_ws, size_t ws_size,
                              hipStream_t stream) {
    const float* feat   = (const float*)d_in[0];
    const float* attn_l = (const float*)d_in[1];
    const float* attn_r = (const float*)d_in[2];
    const int*   src    = (const int*)d_in[3];
    const int*   dst    = (const int*)d_in[4];
    float* out = (float*)d_out;

    int n_edges = in_sizes[3];
    int n_nodes = out_size / (HEADS * DIM);
    int nh = n_nodes * HEADS;

    // Workspace: el_n[8N] f32 | er_n[8N] f32 | rowptr[N+1] | (align16)
    //            | feat_ph [8][N][32] fp16 = nh*64 B | a_ph[8][E] bf16
    char* ws = (char*)d_ws;
    float* el_n = (float*)ws;                     ws += (size_t)nh * 4;
    float* er_n = (float*)ws;                     ws += (size_t)nh * 4;
    int* rowptr = (int*)ws;                       ws += (size_t)(n_nodes + 1) * 4;
    ws = (char*)(((uintptr_t)ws + 15) & ~(uintptr_t)15);
    uint2* feat_ph2 = (uint2*)ws;                 ws += (size_t)nh * 64;
    unsigned short* a_ph = (unsigned short*)ws;

    int nb_logits = (n_nodes + 3) / 4;            // 1 wave/node, 4 per block
    int nb_rowptr = (n_edges + 255) / 256;
    hipLaunchKernelGGL(gat_prep_kernel,
                       dim3(nb_logits + nb_rowptr), dim3(256), 0, stream,
                       (const float4*)feat, (const float4*)attn_l,
                       (const float4*)attn_r, el_n, er_n, feat_ph2,
                       dst, rowptr, n_nodes, n_edges, nb_logits);

    hipLaunchKernelGGL(gat_wden_kernel,
                       dim3((n_nodes + 3) / 4), dim3(256), 0, stream,
                       el_n, er_n, src, rowptr, a_ph, n_nodes, n_edges);

    // 8 heads x waves(8 segments each); h = blockIdx & 7 (XCD partition)
    int waves_per_head = (n_nodes + 7) / 8;
    int blocks = 8 * ((waves_per_head + 3) / 4);
    hipLaunchKernelGGL(gat_aggregate_kernel,
                       dim3(blocks), dim3(256), 0, stream,
                       feat_ph2, a_ph, src, rowptr, (f32x4*)out,
                       n_nodes, n_edges);
}

// Round 14
// 110.176 us; speedup vs baseline: 1.2312x; 1.2312x over previous
//
#include <hip/hip_runtime.h>
#include <hip/hip_fp16.h>
#include <math.h>

#define HEADS 8
#define DIM 32
#define NEG_SLOPE 0.2f

typedef float f32x4 __attribute__((ext_vector_type(4)));

__device__ inline float2 u2f2(unsigned int u) {
    __half2 h = __builtin_bit_cast(__half2, u);
    return __half22float2(h);
}
__device__ inline unsigned short f2bf(float f) {       // RNE f32 -> bf16
    unsigned int u = __builtin_bit_cast(unsigned int, f);
    u += 0x7FFFu + ((u >> 16) & 1u);
    return (unsigned short)(u >> 16);
}
__device__ inline float bf2f(unsigned short b) {
    unsigned int u = ((unsigned int)b) << 16;
    return __builtin_bit_cast(float, u);
}

// Prep (merged): blocks [0, nb_logits): one wave per node — logits el/er in
// [node][8] layout and fp16 feat node-major feat_h[node][256] (512B rows).
// Blocks [nb_logits, ...): CSR rowptr from sorted dst_idx (edge-parallel).
__global__ __launch_bounds__(256) void gat_prep_kernel(
    const float4* __restrict__ feat4,    // node row = 64 float4
    const float4* __restrict__ attn_l4,  // 64 float4 (8 heads x 8)
    const float4* __restrict__ attn_r4,
    float* __restrict__ el_n,            // [n_nodes][8]
    float* __restrict__ er_n,            // [n_nodes][8]
    uint2* __restrict__ feat_h2,         // [n_nodes][64] uint2 (fp16)
    const int* __restrict__ dst,
    int* __restrict__ rowptr,
    int n_nodes, int n_edges, int nb_logits) {
    int b = blockIdx.x;
    if (b < nb_logits) {
        int wid = (b * 256 + threadIdx.x) >> 6;
        if (wid >= n_nodes) return;
        int lane = threadIdx.x & 63;
        int h = lane >> 3;
        int q = lane & 7;

        float4 al = attn_l4[lane];
        float4 ar = attn_r4[lane];
        float4 v  = feat4[(size_t)wid * 64 + lane];

        float sl = v.x * al.x + v.y * al.y + v.z * al.z + v.w * al.w;
        float sr = v.x * ar.x + v.y * ar.y + v.z * ar.z + v.w * ar.w;
#pragma unroll
        for (int off = 1; off < 8; off <<= 1) {
            sl += __shfl_xor(sl, off, 64);
            sr += __shfl_xor(sr, off, 64);
        }
        if (q == 0) {
            el_n[(unsigned)wid * 8 + h] = sl;
            er_n[(unsigned)wid * 8 + h] = sr;
        }
        uint2 o;
        o.x = __builtin_bit_cast(unsigned int, __floats2half2_rn(v.x, v.y));
        o.y = __builtin_bit_cast(unsigned int, __floats2half2_rn(v.z, v.w));
        feat_h2[(size_t)wid * 64 + lane] = o;
    } else {
        int e = (b - nb_logits) * 256 + threadIdx.x;
        if (e >= n_edges) return;
        int d = dst[e];
        int prev = (e > 0) ? dst[e - 1] : -1;
        for (int v = prev + 1; v <= d; ++v) rowptr[v] = e;
        if (e == n_edges - 1) {
            for (int v = d + 1; v <= n_nodes; ++v) rowptr[v] = n_edges;
        }
    }
}

// wprep: one wave per dst node, single pass. Lane (s = lane>>3 edge-slot,
// h = lane&7). Computes w = exp(lrelu(el[u]+er[v])) once per (edge,head),
// stores bf16 EDGE-MAJOR w_e[e][8] (agg reads one 16B line per edge), and
// inv_den[v][8] = 1/sum(bf16-rounded w) via shfl_xor(8,16,32) reduce.
// Moves the el gather + exp + lrelu + denom out of the 81us aggregate.
__global__ __launch_bounds__(256) void gat_wprep_kernel(
    const float* __restrict__ el_n,      // [n_nodes][8]
    const float* __restrict__ er_n,      // [n_nodes][8]
    const int* __restrict__ src_idx,
    const int* __restrict__ rowptr,
    unsigned short* __restrict__ w_e,    // [n_edges][8] bf16
    float* __restrict__ inv_den,         // [n_nodes][8]
    int n_nodes) {
    int vraw = (blockIdx.x * blockDim.x + threadIdx.x) >> 6;
    if (vraw >= n_nodes) return;
    int v = __builtin_amdgcn_readfirstlane(vraw);
    int lane = threadIdx.x & 63;
    int s = lane >> 3;
    int h = lane & 7;

    int start = __builtin_amdgcn_readfirstlane(rowptr[v]);
    int end   = __builtin_amdgcn_readfirstlane(rowptr[v + 1]);
    if (start == end) return;            // empty: agg writes zeros, inv unused

    float er_vh = er_n[(unsigned)v * 8 + h];

    float den = 0.f;
    for (int e0 = start; e0 < end; e0 += 8) {
        int e = e0 + s;
        int ee = e < end ? e : (end - 1);
        int u = src_idx[ee];
        float sc = el_n[(unsigned)u * 8 + h] + er_vh;
        sc = fmaxf(sc, NEG_SLOPE * sc);
        float w = __expf(sc);
        unsigned short wb = f2bf(w);
        float wf = bf2f(wb);
        if (e < end) {
            w_e[(size_t)e * 8 + h] = wb;
            den += wf;
        }
    }
    den += __shfl_xor(den, 8, 64);
    den += __shfl_xor(den, 16, 64);
    den += __shfl_xor(den, 32, 64);
    if (s == 0) {
        inv_den[(unsigned)v * 8 + h] = 1.f / den;
    }
}

// Aggregate (family A, R7 structure, gather-only hot loop): one wave per
// node; lane = (h = lane>>3, d4 = lane&7); per edge: uniform src s_load +
// one 16B w_e line + 512B feat row gather + FMA. No exp/lrelu/el/denom.
// Epilogue: multiply by precomputed inv_den[v][h]. Unroll-8, clamp + w=0
// tail predication.
__global__ __launch_bounds__(256) void gat_aggregate_kernel(
    const uint2* __restrict__ feat_h,    // [n_nodes][64] uint2
    const unsigned short* __restrict__ w_e,   // [n_edges][8] bf16
    const float* __restrict__ inv_den,        // [n_nodes][8]
    const int* __restrict__ src_idx,
    const int* __restrict__ rowptr,
    f32x4* __restrict__ out4,            // [n_nodes][64] float4-units
    int n_nodes) {
    int vraw = (blockIdx.x * blockDim.x + threadIdx.x) >> 6;
    if (vraw >= n_nodes) return;
    int v = __builtin_amdgcn_readfirstlane(vraw);
    int lane = threadIdx.x & 63;
    int h = lane >> 3;

    int start = __builtin_amdgcn_readfirstlane(rowptr[v]);
    int end   = __builtin_amdgcn_readfirstlane(rowptr[v + 1]);

    unsigned obase = ((unsigned)v << 6) + (unsigned)lane;
    if (start == end) {
        f32x4 z = {0.f, 0.f, 0.f, 0.f};
        __builtin_nontemporal_store(z, &out4[obase]);
        return;
    }
    int endm1 = end - 1;

    f32x4 acc0 = {0.f, 0.f, 0.f, 0.f};
    f32x4 acc1 = {0.f, 0.f, 0.f, 0.f};

    for (int e = start; e < end; e += 8) {
        int   idx[8];
        uint2 fr[8];
        float wv[8];
#pragma unroll
        for (int i = 0; i < 8; ++i) {
            int ee = (e + i < endm1) ? (e + i) : endm1;   // scalar clamp
            idx[i] = src_idx[ee];                          // uniform -> s_load
            wv[i]  = bf2f(w_e[(size_t)ee * 8 + h]);        // one 16B line
            if (e + i > endm1) wv[i] = 0.f;
        }
#pragma unroll
        for (int i = 0; i < 8; ++i) {
            fr[i] = feat_h[((unsigned)idx[i] << 6) + (unsigned)lane];
        }
#pragma unroll
        for (int i = 0; i < 8; ++i) {
            float w = wv[i];
            float2 lo = u2f2(fr[i].x);
            float2 hi = u2f2(fr[i].y);
            if (i & 1) {
                acc1.x += w * lo.x; acc1.y += w * lo.y;
                acc1.z += w * hi.x; acc1.w += w * hi.y;
            } else {
                acc0.x += w * lo.x; acc0.y += w * lo.y;
                acc0.z += w * hi.x; acc0.w += w * hi.y;
            }
        }
    }
    float invd = inv_den[((unsigned)v << 3) + (unsigned)h];
    f32x4 r = acc0 + acc1;
    r.x *= invd; r.y *= invd; r.z *= invd; r.w *= invd;
    __builtin_nontemporal_store(r, &out4[obase]);
}

extern "C" void kernel_launch(void* const* d_in, const int* in_sizes, int n_in,
                              void* d_out, int out_size, void* d_ws, size_t ws_size,
                              hipStream_t stream) {
    const float* feat   = (const float*)d_in[0];
    const float* attn_l = (const float*)d_in[1];
    const float* attn_r = (const float*)d_in[2];
    const int*   src    = (const int*)d_in[3];
    const int*   dst    = (const int*)d_in[4];
    float* out = (float*)d_out;

    int n_edges = in_sizes[3];
    int n_nodes = out_size / (HEADS * DIM);
    int nh = n_nodes * HEADS;

    // Workspace: el_n[8N] f32 | er_n[8N] f32 | inv_den[8N] f32 | rowptr[N+1]
    //            | (align16) | feat_h [N][256] fp16 = nh*64 B | w_e[E][8] bf16
    char* ws = (char*)d_ws;
    float* el_n = (float*)ws;                     ws += (size_t)nh * 4;
    float* er_n = (float*)ws;                     ws += (size_t)nh * 4;
    float* inv_den = (float*)ws;                  ws += (size_t)nh * 4;
    int* rowptr = (int*)ws;                       ws += (size_t)(n_nodes + 1) * 4;
    ws = (char*)(((uintptr_t)ws + 15) & ~(uintptr_t)15);
    uint2* feat_h2 = (uint2*)ws;                  ws += (size_t)nh * 64;
    unsigned short* w_e = (unsigned short*)ws;    // n_edges*16 B

    int nb_logits = (n_nodes + 3) / 4;            // 1 wave/node, 4 per block
    int nb_rowptr = (n_edges + 255) / 256;
    hipLaunchKernelGGL(gat_prep_kernel,
                       dim3(nb_logits + nb_rowptr), dim3(256), 0, stream,
                       (const float4*)feat, (const float4*)attn_l,
                       (const float4*)attn_r, el_n, er_n, feat_h2,
                       dst, rowptr, n_nodes, n_edges, nb_logits);

    hipLaunchKernelGGL(gat_wprep_kernel,
                       dim3((n_nodes + 3) / 4), dim3(256), 0, stream,
                       el_n, er_n, src, rowptr, w_e, inv_den, n_nodes);

    hipLaunchKernelGGL(gat_aggregate_kernel,
                       dim3((n_nodes + 3) / 4), dim3(256), 0, stream,
                       feat_h2, w_e, inv_den, src, rowptr, (f32x4*)out,
                       n_nodes);
}

// Round 15
// 96.066 us; speedup vs baseline: 1.4120x; 1.1469x over previous
//
#include <hip/hip_runtime.h>
#include <hip/hip_fp16.h>
#include <math.h>

#define HEADS 8
#define DIM 32
#define NEG_SLOPE 0.2f

typedef float f32x4 __attribute__((ext_vector_type(4)));

__device__ inline float2 u2f2(unsigned int u) {
    __half2 h = __builtin_bit_cast(__half2, u);
    return __half22float2(h);
}
__device__ inline unsigned short f2bf(float f) {       // RNE f32 -> bf16
    unsigned int u = __builtin_bit_cast(unsigned int, f);
    u += 0x7FFFu + ((u >> 16) & 1u);
    return (unsigned short)(u >> 16);
}
__device__ inline float bf2f(unsigned short b) {
    unsigned int u = ((unsigned int)b) << 16;
    return __builtin_bit_cast(float, u);
}

// Prep: one wave per node — logits el/er in [node][8] layout and fp16 feat
// node-major feat_h[node][256] (512B rows, coalesced uint2/lane).
__global__ __launch_bounds__(256) void gat_prep_kernel(
    const float4* __restrict__ feat4,    // node row = 64 float4
    const float4* __restrict__ attn_l4,  // 64 float4 (8 heads x 8)
    const float4* __restrict__ attn_r4,
    float* __restrict__ el_n,            // [n_nodes][8]
    float* __restrict__ er_n,            // [n_nodes][8]
    uint2* __restrict__ feat_h2,         // [n_nodes][64] uint2 (fp16)
    int n_nodes) {
    int wid = (blockIdx.x * blockDim.x + threadIdx.x) >> 6;
    if (wid >= n_nodes) return;
    int lane = threadIdx.x & 63;
    int h = lane >> 3;
    int q = lane & 7;

    float4 al = attn_l4[lane];
    float4 ar = attn_r4[lane];
    float4 v  = feat4[(size_t)wid * 64 + lane];

    float sl = v.x * al.x + v.y * al.y + v.z * al.z + v.w * al.w;
    float sr = v.x * ar.x + v.y * ar.y + v.z * ar.z + v.w * ar.w;
#pragma unroll
    for (int off = 1; off < 8; off <<= 1) {
        sl += __shfl_xor(sl, off, 64);
        sr += __shfl_xor(sr, off, 64);
    }
    if (q == 0) {
        el_n[(unsigned)wid * 8 + h] = sl;
        er_n[(unsigned)wid * 8 + h] = sr;
    }
    uint2 o;
    o.x = __builtin_bit_cast(unsigned int, __floats2half2_rn(v.x, v.y));
    o.y = __builtin_bit_cast(unsigned int, __floats2half2_rn(v.z, v.w));
    feat_h2[(size_t)wid * 64 + lane] = o;
}

// Edge-parallel: one thread per edge. (a) CSR rowptr build from sorted dst.
// (b) w_e[e][0..7] = bf16(exp(lrelu(el[u][h]+er[v][h]))) packed as one 16B
// store. el gather hits the L2-resident 1.6MB table; er is sequential-ish.
// Replaces R14's 18us wave-serial wprep (predicted ~7us).
__global__ __launch_bounds__(256) void gat_edgew_kernel(
    const float4* __restrict__ el_n4,    // [n_nodes][2] float4
    const float4* __restrict__ er_n4,
    const int* __restrict__ src_idx,
    const int* __restrict__ dst_idx,
    int* __restrict__ rowptr,
    uint4* __restrict__ w_e4,            // [n_edges] x 16B (8 bf16)
    int n_edges, int n_nodes) {
    int e = blockIdx.x * blockDim.x + threadIdx.x;
    if (e >= n_edges) return;
    int d = dst_idx[e];
    int prev = (e > 0) ? dst_idx[e - 1] : -1;
    for (int v = prev + 1; v <= d; ++v) rowptr[v] = e;
    if (e == n_edges - 1) {
        for (int v = d + 1; v <= n_nodes; ++v) rowptr[v] = n_edges;
    }

    unsigned u = (unsigned)src_idx[e];
    float4 elA = el_n4[u * 2], elB = el_n4[u * 2 + 1];
    float4 erA = er_n4[(unsigned)d * 2], erB = er_n4[(unsigned)d * 2 + 1];
    float s[8];
    s[0] = elA.x + erA.x; s[1] = elA.y + erA.y;
    s[2] = elA.z + erA.z; s[3] = elA.w + erA.w;
    s[4] = elB.x + erB.x; s[5] = elB.y + erB.y;
    s[6] = elB.z + erB.z; s[7] = elB.w + erB.w;
    unsigned short wb[8];
#pragma unroll
    for (int h = 0; h < 8; ++h) {
        float t = fmaxf(s[h], NEG_SLOPE * s[h]);   // leaky relu
        wb[h] = f2bf(__expf(t));
    }
    uint4 pk;
    pk.x = (unsigned)wb[0] | ((unsigned)wb[1] << 16);
    pk.y = (unsigned)wb[2] | ((unsigned)wb[3] << 16);
    pk.z = (unsigned)wb[4] | ((unsigned)wb[5] << 16);
    pk.w = (unsigned)wb[6] | ((unsigned)wb[7] << 16);
    w_e4[e] = pk;
}

// Aggregate: one wave per node; lane = (h = lane>>3, d4 = lane&7); per edge:
// uniform src s_load + one 16B w_e line (broadcast per head) + 512B feat row
// gather + FMA; den accumulated inline (1 add/edge, free at 21% VALU).
// Unroll-8, clamp + w=0 tail predication. Divide once in epilogue.
__global__ __launch_bounds__(256) void gat_aggregate_kernel(
    const uint2* __restrict__ feat_h,         // [n_nodes][64] uint2
    const unsigned short* __restrict__ w_e,   // [n_edges][8] bf16
    const int* __restrict__ src_idx,
    const int* __restrict__ rowptr,
    f32x4* __restrict__ out4,                 // [n_nodes][64] float4-units
    int n_nodes) {
    int vraw = (blockIdx.x * blockDim.x + threadIdx.x) >> 6;
    if (vraw >= n_nodes) return;
    int v = __builtin_amdgcn_readfirstlane(vraw);
    int lane = threadIdx.x & 63;
    int h = lane >> 3;

    int start = __builtin_amdgcn_readfirstlane(rowptr[v]);
    int end   = __builtin_amdgcn_readfirstlane(rowptr[v + 1]);

    unsigned obase = ((unsigned)v << 6) + (unsigned)lane;
    if (start == end) {
        f32x4 z = {0.f, 0.f, 0.f, 0.f};
        __builtin_nontemporal_store(z, &out4[obase]);
        return;
    }
    int endm1 = end - 1;

    float denA = 0.f, denB = 0.f;
    f32x4 acc0 = {0.f, 0.f, 0.f, 0.f};
    f32x4 acc1 = {0.f, 0.f, 0.f, 0.f};

    for (int e = start; e < end; e += 8) {
        int   idx[8];
        uint2 fr[8];
        float wv[8];
#pragma unroll
        for (int i = 0; i < 8; ++i) {
            int ee = (e + i < endm1) ? (e + i) : endm1;   // scalar clamp
            idx[i] = src_idx[ee];                          // uniform -> s_load
            wv[i]  = bf2f(w_e[(size_t)ee * 8 + h]);        // one 16B line
            if (e + i > endm1) wv[i] = 0.f;
        }
#pragma unroll
        for (int i = 0; i < 8; ++i) {
            fr[i] = feat_h[((unsigned)idx[i] << 6) + (unsigned)lane];
        }
#pragma unroll
        for (int i = 0; i < 8; ++i) {
            float w = wv[i];
            float2 lo = u2f2(fr[i].x);
            float2 hi = u2f2(fr[i].y);
            if (i & 1) {
                denB += w;
                acc1.x += w * lo.x; acc1.y += w * lo.y;
                acc1.z += w * hi.x; acc1.w += w * hi.y;
            } else {
                denA += w;
                acc0.x += w * lo.x; acc0.y += w * lo.y;
                acc0.z += w * hi.x; acc0.w += w * hi.y;
            }
        }
    }
    float invd = 1.f / (denA + denB);
    f32x4 r = acc0 + acc1;
    r.x *= invd; r.y *= invd; r.z *= invd; r.w *= invd;
    __builtin_nontemporal_store(r, &out4[obase]);
}

extern "C" void kernel_launch(void* const* d_in, const int* in_sizes, int n_in,
                              void* d_out, int out_size, void* d_ws, size_t ws_size,
                              hipStream_t stream) {
    const float* feat   = (const float*)d_in[0];
    const float* attn_l = (const float*)d_in[1];
    const float* attn_r = (const float*)d_in[2];
    const int*   src    = (const int*)d_in[3];
    const int*   dst    = (const int*)d_in[4];
    float* out = (float*)d_out;

    int n_edges = in_sizes[3];
    int n_nodes = out_size / (HEADS * DIM);
    int nh = n_nodes * HEADS;

    // Workspace: el_n[8N] f32 | er_n[8N] f32 | rowptr[N+1] | (align16)
    //            | feat_h [N][256] fp16 = nh*64 B | w_e[E][8] bf16 = E*16 B
    char* ws = (char*)d_ws;
    float* el_n = (float*)ws;                     ws += (size_t)nh * 4;
    float* er_n = (float*)ws;                     ws += (size_t)nh * 4;
    int* rowptr = (int*)ws;                       ws += (size_t)(n_nodes + 1) * 4;
    ws = (char*)(((uintptr_t)ws + 15) & ~(uintptr_t)15);
    uint2* feat_h2 = (uint2*)ws;                  ws += (size_t)nh * 64;
    unsigned short* w_e = (unsigned short*)ws;

    hipLaunchKernelGGL(gat_prep_kernel,
                       dim3((n_nodes + 3) / 4), dim3(256), 0, stream,
                       (const float4*)feat, (const float4*)attn_l,
                       (const float4*)attn_r, el_n, er_n, feat_h2, n_nodes);

    hipLaunchKernelGGL(gat_edgew_kernel,
                       dim3((n_edges + 255) / 256), dim3(256), 0, stream,
                       (const float4*)el_n, (const float4*)er_n, src, dst,
                       rowptr, (uint4*)w_e, n_edges, n_nodes);

    hipLaunchKernelGGL(gat_aggregate_kernel,
                       dim3((n_nodes + 3) / 4), dim3(256), 0, stream,
                       feat_h2, w_e, src, rowptr, (f32x4*)out, n_nodes);
}